// Round 5
// baseline (2613.658 us; speedup 1.0000x reference)
//
#include <hip/hip_runtime.h>
#include <cstdint>
#include <cstddef>

typedef __bf16 bf16_t;
typedef __attribute__((ext_vector_type(8))) __bf16 bf16x8;
typedef __attribute__((ext_vector_type(4))) float f32x4;

__device__ __forceinline__ void async_cp16(const void* g, void* l) {
    __builtin_amdgcn_global_load_lds(
        (const __attribute__((address_space(1))) void*)g,
        (__attribute__((address_space(3))) void*)l,
        16, 0, 0);
}

__device__ __forceinline__ float fast_tanh(float x) {
    float ax = fabsf(x);
    float e = __expf(-2.f * ax);
    float t = (1.f - e) / (1.f + e);
    return x < 0.f ? -t : t;
}
__device__ __forceinline__ float fast_sig(float x) {
    return 1.f / (1.f + __expf(-x));
}

// ---------------- conversion kernels ----------------
__global__ void k_cvt_transpose(const float* __restrict__ src, bf16_t* __restrict__ dst,
                                int K, int N) {
    int idx = blockIdx.x * 256 + threadIdx.x;
    if (idx >= K * N) return;
    int k = idx / N, n = idx - k * N;
    dst[(size_t)n * K + k] = (bf16_t)src[idx];
}

__global__ void k_cvt_flat(const float* __restrict__ src, bf16_t* __restrict__ dst, int n) {
    int idx = blockIdx.x * 256 + threadIdx.x;
    if (idx >= n) return;
    dst[idx] = (bf16_t)src[idx];
}

__global__ void k_build_wrz(const float* __restrict__ Wih, const float* __restrict__ Whh,
                            const float* __restrict__ bih, const float* __restrict__ bhh,
                            bf16_t* __restrict__ wrz, float* __restrict__ brz) {
    int idx = blockIdx.x * 256 + threadIdx.x;
    if (idx >= 2048 * 1280) return;
    int n = idx / 1280, c = idx - n * 1280;
    float v = (c < 256) ? Wih[(size_t)n * 256 + c] : Whh[(size_t)n * 1024 + (c - 256)];
    wrz[idx] = (bf16_t)v;
    if (c == 0) brz[n] = bih[n] + bhh[n];
}

__global__ void k_cvt_x(const float* __restrict__ xt, bf16_t* __restrict__ xh, int B) {
    int idx = blockIdx.x * 256 + threadIdx.x;
    if (idx >= B * 256) return;
    int b = idx >> 8, c = idx & 255;
    xh[(size_t)b * 1280 + c] = (bf16_t)xt[idx];
}

__global__ void k_cvt_h0(const float* __restrict__ state, bf16_t* __restrict__ h0b, int B) {
    int idx = blockIdx.x * 256 + threadIdx.x;
    if (idx >= B * 1024) return;
    int b = idx >> 10, j = idx & 1023;
    h0b[idx] = (bf16_t)state[(size_t)b * 1040 + 16 + j];
}

// ---------------- GEMM: C(MxN) = A(MxK) * Bt(NxK)^T, bf16 in, f32 acc ----------------
// 128x256 tile, BK=32, 512 threads (8 waves, 2M x 4N; wave = 64x64 output).
// Register-double-buffered fragment pipeline: per window, ds_read tile t+1's frags
// into the spare reg set while MFMAing tile t's regs.  3-slot LDS (72 KiB), prefetch
// depth 2, counted vmcnt(3) + raw s_barrier + lgkmcnt(0) drain at window end
// (drain makes the 3-slot WAR distance safe: reads of slot s complete before
// barrier b_{s+1}; overwrite of slot s issues after b_{s+1}).
// XOR bank swizzle as rounds 3/4 (verified 0 conflicts).
enum { EPI_TANH = 0, EPI_RK4 = 1, EPI_SIG = 2, EPI_BIASBF = 3, EPI_FIN = 4 };

template <int EPI, int STAGE>
__global__ __launch_bounds__(512, 1) void gemm128(
    const bf16_t* __restrict__ A, int lda,
    const bf16_t* __restrict__ Bt,
    int N, int K,
    const float* __restrict__ bias,
    bf16_t* __restrict__ obf,
    const bf16_t* __restrict__ h0b,   // B x 1024 bf16 (RK4 stages 0-2)
    const float* __restrict__ state,  // f32, ld 1040 (RK4 stage 3 only)
    bf16_t* __restrict__ kacc,        // B x 1024 bf16 (k-sum)
    float* __restrict__ outp,         // f32 out, ld 1040
    bf16_t* __restrict__ xh_ht,       // = xh + 256 (ld 1280): stage-3 write / FIN ht read
    const bf16_t* __restrict__ rz,    // B x 2048 bf16 (FIN)
    const bf16_t* __restrict__ inb)   // B x 1024 bf16 (FIN)
{
    __shared__ __align__(16) bf16_t As[3][4096];   // 3 slots x 128 rows x 32 k
    __shared__ __align__(16) bf16_t Bs[3][8192];   // 3 slots x 256 rows x 32 k

    const int tid  = threadIdx.x;
    const int lane = tid & 63;
    const int wv   = tid >> 6;

    // XCD-aware bijective swizzle (all grids here have nwg % 8 == 0)
    const int gx  = gridDim.x;
    int bid = blockIdx.y * gx + blockIdx.x;
    const int nwg = gx * gridDim.y;
    if ((nwg & 7) == 0) {
        bid = (bid & 7) * (nwg >> 3) + (bid >> 3);
    }
    const int bm = (bid / gx) << 7;   // 128-row tiles
    const int bn = (bid % gx) << 8;   // 256-col tiles

    const int wm = (wv >> 2) << 6;    // 0 or 64
    const int wn = (wv & 3) << 6;     // 0,64,128,192

    f32x4 acc[4][4] = {};

    // ---- staging (linear LDS dest, swizzled global source) ----
    const int srow = tid >> 2;                        // 0..127
    const int s4   = tid & 3;
    const int scw  = (s4 ^ ((srow >> 1) & 3)) << 3;   // swizzled col (elems)
    const bf16_t* gA0 = A  + (size_t)(bm + srow) * lda + scw;
    const bf16_t* gB0 = Bt + (size_t)(bn + srow) * K + scw;
    const bf16_t* gB1 = gB0 + (size_t)128 * K;        // rows+128: same swizzle term
    const int ldsOff = tid << 3;                      // 16B per thread

    // 3 load-instructions per wave per K-tile  ->  steady-state gate = vmcnt(3)
#define STAGE_KT(kk) do {                                               \
        const int _sl = (kk) % 3; const size_t _ko = (size_t)(kk) << 5; \
        async_cp16(gA0 + _ko, (void*)&As[_sl][ldsOff]);                 \
        async_cp16(gB0 + _ko, (void*)&Bs[_sl][ldsOff]);                 \
        async_cp16(gB1 + _ko, (void*)&Bs[_sl][4096 + ldsOff]);          \
    } while (0)

    // ---- fragment LDS offsets (within a slot), swizzled read ----
    const int fr = lane & 15;
    const int kg = lane >> 4;
    const int ra = wm + fr;
    const int rb = wn + fr;
    const int aoff0 = ra * 32 + ((kg ^ ((ra >> 1) & 3)) << 3);
    const int boff0 = rb * 32 + ((kg ^ ((rb >> 1) & 3)) << 3);

#define READ_FRAGS(da, db, sl) do {                                     \
        const bf16_t* _as = &As[sl][0];                                 \
        const bf16_t* _bs = &Bs[sl][0];                                 \
        _Pragma("unroll")                                               \
        for (int i = 0; i < 4; ++i) da[i] = *(const bf16x8*)(_as + aoff0 + i * 512); \
        _Pragma("unroll")                                               \
        for (int j = 0; j < 4; ++j) db[j] = *(const bf16x8*)(_bs + boff0 + j * 512); \
    } while (0)

#define MFMA_ALL(fa, fb) do {                                           \
        __builtin_amdgcn_s_setprio(1);                                  \
        _Pragma("unroll")                                               \
        for (int i = 0; i < 4; ++i)                                     \
        _Pragma("unroll")                                               \
        for (int j = 0; j < 4; ++j)                                     \
            acc[i][j] = __builtin_amdgcn_mfma_f32_16x16x32_bf16(fa[i], fb[j], acc[i][j], 0, 0, 0); \
        __builtin_amdgcn_s_setprio(0);                                  \
    } while (0)

    const int NT = K >> 5;   // always even here (8/32/40/64)

    bf16x8 a0[4], b0[4], a1[4], b1[4];

    // prologue: window 0 (read slot 0, no MFMA yet)
    STAGE_KT(0);
    STAGE_KT(1);
    asm volatile("s_waitcnt vmcnt(3)" ::: "memory");   // slot 0 landed
    __builtin_amdgcn_s_barrier();
    READ_FRAGS(a0, b0, 0);
    if (NT > 2) STAGE_KT(2);
    asm volatile("s_waitcnt lgkmcnt(0)" ::: "memory"); // slot-0 reads serviced pre-b1

    for (int kt = 1; kt < NT; kt += 2) {
        // ---- window kt: read frags(kt) -> set1, MFMA tile kt-1 (set0) ----
        if (kt + 1 < NT) asm volatile("s_waitcnt vmcnt(3)" ::: "memory");
        else             asm volatile("s_waitcnt vmcnt(0)" ::: "memory");
        __builtin_amdgcn_s_barrier();
        READ_FRAGS(a1, b1, kt % 3);
        if (kt + 2 < NT) STAGE_KT(kt + 2);
        MFMA_ALL(a0, b0);
        asm volatile("s_waitcnt lgkmcnt(0)" ::: "memory");

        // ---- window kt+1: read frags(kt+1) -> set0, MFMA tile kt (set1) ----
        if (kt + 1 < NT) {
            if (kt + 2 < NT) asm volatile("s_waitcnt vmcnt(3)" ::: "memory");
            else             asm volatile("s_waitcnt vmcnt(0)" ::: "memory");
            __builtin_amdgcn_s_barrier();
            READ_FRAGS(a0, b0, (kt + 1) % 3);
            if (kt + 3 < NT) STAGE_KT(kt + 3);
            MFMA_ALL(a1, b1);
            asm volatile("s_waitcnt lgkmcnt(0)" ::: "memory");
        }
    }
    // NT even -> last read went into set1 at window NT-1; finish tile NT-1
    MFMA_ALL(a1, b1);

#undef STAGE_KT
#undef READ_FRAGS
#undef MFMA_ALL

    // C/D layout (verified m89/m91): col = lane&15, row = (lane>>4)*4 + reg
    const int orow0 = bm + wm + (kg << 2);
    const int ocol0 = bn + wn + fr;
#pragma unroll
    for (int i = 0; i < 4; ++i) {
#pragma unroll
        for (int j = 0; j < 4; ++j) {
#pragma unroll
            for (int r = 0; r < 4; ++r) {
                const int row = orow0 + i * 16 + r;
                const int col = ocol0 + j * 16;
                const float c = acc[i][j][r];
                if constexpr (EPI == EPI_TANH) {
                    obf[(size_t)row * N + col] = (bf16_t)fast_tanh(c + bias[col]);
                } else if constexpr (EPI == EPI_RK4) {
                    const float kk = c + bias[col];
                    const size_t hidx = ((size_t)row << 10) + col;
                    if constexpr (STAGE == 0) {
                        const float h0 = (float)h0b[hidx];
                        kacc[hidx] = (bf16_t)kk;
                        obf[hidx] = (bf16_t)(h0 + 0.05f * kk);
                    } else if constexpr (STAGE == 1) {
                        const float h0 = (float)h0b[hidx];
                        kacc[hidx] = (bf16_t)((float)kacc[hidx] + 2.f * kk);
                        obf[hidx] = (bf16_t)(h0 + 0.05f * kk);
                    } else if constexpr (STAGE == 2) {
                        const float h0 = (float)h0b[hidx];
                        kacc[hidx] = (bf16_t)((float)kacc[hidx] + 2.f * kk);
                        obf[hidx] = (bf16_t)(h0 + 0.1f * kk);
                    } else {
                        const float h0 = state[(size_t)row * 1040 + 16 + col];
                        const float ht = h0 + (0.1f / 6.f) * ((float)kacc[hidx] + kk);
                        outp[(size_t)row * 1040 + 16 + col] = ht;
                        xh_ht[(size_t)row * 1280 + col] = (bf16_t)ht;
                    }
                } else if constexpr (EPI == EPI_SIG) {
                    obf[(size_t)row * N + col] = (bf16_t)fast_sig(c + bias[col]);
                } else if constexpr (EPI == EPI_BIASBF) {
                    obf[(size_t)row * N + col] = (bf16_t)(c + bias[col]);
                } else {  // EPI_FIN
                    const float hn  = c + bias[col];
                    const float r_  = (float)rz[((size_t)row << 11) + col];
                    const float z_  = (float)rz[((size_t)row << 11) + 1024 + col];
                    const float inv = (float)inb[((size_t)row << 10) + col];
                    const float nn  = fast_tanh(inv + r_ * hn);
                    const float htv = (float)xh_ht[(size_t)row * 1280 + col];
                    outp[(size_t)row * 1040 + 16 + col] = (1.f - z_) * nn + z_ * htv;
                }
            }
        }
    }
}

// ---------------- readout: out[:, :16] ----------------
__global__ void k_ly(const float* __restrict__ outh, const float* __restrict__ state,
                     const float* __restrict__ Wly, const float* __restrict__ bly,
                     const int* __restrict__ y_type, float* __restrict__ outp, int B) {
    int t = blockIdx.x * 256 + threadIdx.x;
    if (t >= B * 16) return;
    int o = t & 15, b = t >> 4;
    const float4* hrow = (const float4*)(outh + (size_t)b * 1040 + 16);
    float s = bly[o];
#pragma unroll 4
    for (int k4 = 0; k4 < 256; ++k4) {
        float4 h = hrow[k4];
        int k = k4 << 2;
        s += h.x * Wly[(k + 0) * 16 + o] + h.y * Wly[(k + 1) * 16 + o]
           + h.z * Wly[(k + 2) * 16 + o] + h.w * Wly[(k + 3) * 16 + o];
    }
    outp[(size_t)b * 1040 + o] = (y_type[o] == 0) ? s : state[(size_t)b * 1040 + o];
}

// ---------------- launcher ----------------
extern "C" void kernel_launch(void* const* d_in, const int* in_sizes, int n_in,
                              void* d_out, int out_size, void* d_ws, size_t ws_size,
                              hipStream_t stream) {
    const float* state = (const float*)d_in[0];
    const float* xt    = (const float*)d_in[1];
    const float* W1    = (const float*)d_in[2];
    const float* b1    = (const float*)d_in[3];
    const float* W2    = (const float*)d_in[4];
    const float* b2    = (const float*)d_in[5];
    const float* Wih   = (const float*)d_in[6];
    const float* Whh   = (const float*)d_in[7];
    const float* bih   = (const float*)d_in[8];
    const float* bhh   = (const float*)d_in[9];
    const float* Wly   = (const float*)d_in[10];
    const float* bly   = (const float*)d_in[11];
    const int*   y_type = (const int*)d_in[12];
    float* out = (float*)d_out;

    const int B = in_sizes[0] / 1040;   // 32768

    char* ws = (char*)d_ws;
    bf16_t* w1t  = (bf16_t*)(ws);                    // 2048 x 1024
    bf16_t* w2t  = (bf16_t*)(ws + 4194304);          // 1024 x 2048
    bf16_t* wrz  = (bf16_t*)(ws + 8388608);          // 2048 x 1280
    bf16_t* win  = (bf16_t*)(ws + 13631488);         // 1024 x 256
    bf16_t* whn  = (bf16_t*)(ws + 14155776);         // 1024 x 1024
    float*  brz  = (float*) (ws + 16252928);         // 2048
    bf16_t* xh   = (bf16_t*)(ws + 16261120);         // B x 1280 ([x | ht_])
    bf16_t* hs   = (bf16_t*)(ws + 100147200);        // B x 1024 (RK4 stage input)
    bf16_t* h0b  = (bf16_t*)(ws + 167256064);        // B x 1024 (h0 bf16; later i_n)
    bf16_t* inbf = h0b;                              // i_n output reuses h0b space
    bf16_t* T    = (bf16_t*)(ws + 234364928);        // B x 2048 (tanh act; later r/z)
    bf16_t* kacc = (bf16_t*)(ws + 368582656);        // B x 1024 (k-sum, bf16)

    // weight prep + input casts
    k_cvt_transpose<<<(1024 * 2048) / 256, 256, 0, stream>>>(W1, w1t, 1024, 2048);
    k_cvt_transpose<<<(2048 * 1024) / 256, 256, 0, stream>>>(W2, w2t, 2048, 1024);
    k_build_wrz<<<(2048 * 1280) / 256, 256, 0, stream>>>(Wih, Whh, bih, bhh, wrz, brz);
    k_cvt_flat<<<(1024 * 256) / 256, 256, 0, stream>>>(Wih + 2048 * 256, win, 1024 * 256);
    k_cvt_flat<<<(1024 * 1024) / 256, 256, 0, stream>>>(Whh + 2048 * 1024, whn, 1024 * 1024);
    k_cvt_x<<<(B * 256) / 256, 256, 0, stream>>>(xt, xh, B);
    k_cvt_h0<<<(B * 1024) / 256, 256, 0, stream>>>(state, h0b, B);

    const dim3 blk(512);
    const int MB = B / 128;   // 256 m-tiles

    // ---- RK4: 4 stages of (tanh GEMM) -> (W2 GEMM + stage epilogue) ----
    gemm128<EPI_TANH, 0><<<dim3(8, MB), blk, 0, stream>>>(h0b, 1024, w1t, 2048, 1024, b1, T,
        nullptr, nullptr, nullptr, nullptr, nullptr, nullptr, nullptr);
    gemm128<EPI_RK4, 0><<<dim3(4, MB), blk, 0, stream>>>(T, 2048, w2t, 1024, 2048, b2, hs,
        h0b, state, kacc, out, xh + 256, nullptr, nullptr);

    gemm128<EPI_TANH, 0><<<dim3(8, MB), blk, 0, stream>>>(hs, 1024, w1t, 2048, 1024, b1, T,
        nullptr, nullptr, nullptr, nullptr, nullptr, nullptr, nullptr);
    gemm128<EPI_RK4, 1><<<dim3(4, MB), blk, 0, stream>>>(T, 2048, w2t, 1024, 2048, b2, hs,
        h0b, state, kacc, out, xh + 256, nullptr, nullptr);

    gemm128<EPI_TANH, 0><<<dim3(8, MB), blk, 0, stream>>>(hs, 1024, w1t, 2048, 1024, b1, T,
        nullptr, nullptr, nullptr, nullptr, nullptr, nullptr, nullptr);
    gemm128<EPI_RK4, 2><<<dim3(4, MB), blk, 0, stream>>>(T, 2048, w2t, 1024, 2048, b2, hs,
        h0b, state, kacc, out, xh + 256, nullptr, nullptr);

    gemm128<EPI_TANH, 0><<<dim3(8, MB), blk, 0, stream>>>(hs, 1024, w1t, 2048, 1024, b1, T,
        nullptr, nullptr, nullptr, nullptr, nullptr, nullptr, nullptr);
    gemm128<EPI_RK4, 3><<<dim3(4, MB), blk, 0, stream>>>(T, 2048, w2t, 1024, 2048, b2, hs,
        h0b, state, kacc, out, xh + 256, nullptr, nullptr);

    // ---- GRU ----
    // r,z gates: [x|ht_] (K=1280) @ wrz^T -> sigmoid -> T (B x 2048 bf16)
    gemm128<EPI_SIG, 0><<<dim3(8, MB), blk, 0, stream>>>(xh, 1280, wrz, 2048, 1280, brz, T,
        nullptr, nullptr, nullptr, nullptr, nullptr, nullptr, nullptr);
    // i_n: x (K=256) @ Wih_n^T + bih_n -> bf16 (into h0b space, h0b dead now)
    gemm128<EPI_BIASBF, 0><<<dim3(4, MB), blk, 0, stream>>>(xh, 1280, win, 1024, 256,
        bih + 2048, inbf, nullptr, nullptr, nullptr, nullptr, nullptr, nullptr, nullptr);
    // h_n GEMM + full GRU merge -> out[:, 16:]
    gemm128<EPI_FIN, 0><<<dim3(4, MB), blk, 0, stream>>>(xh + 256, 1280, whn, 1024, 1024,
        bhh + 2048, nullptr, nullptr, nullptr, nullptr, out, xh + 256, T, inbf);

    // ---- readout out[:, :16] ----
    k_ly<<<(B * 16) / 256, 256, 0, stream>>>(out, state, Wly, bly, y_type, out, B);
}

// Round 6
// 2373.664 us; speedup vs baseline: 1.1011x; 1.1011x over previous
//
#include <hip/hip_runtime.h>
#include <cstdint>
#include <cstddef>

typedef __bf16 bf16_t;
typedef __attribute__((ext_vector_type(8))) __bf16 bf16x8;
typedef __attribute__((ext_vector_type(4))) float f32x4;

__device__ __forceinline__ void async_cp16(const void* g, void* l) {
    __builtin_amdgcn_global_load_lds(
        (const __attribute__((address_space(1))) void*)g,
        (__attribute__((address_space(3))) void*)l,
        16, 0, 0);
}

__device__ __forceinline__ float fast_tanh(float x) {
    float ax = fabsf(x);
    float e = __expf(-2.f * ax);
    float t = (1.f - e) / (1.f + e);
    return x < 0.f ? -t : t;
}
__device__ __forceinline__ float fast_sig(float x) {
    return 1.f / (1.f + __expf(-x));
}

// ---------------- conversion kernels ----------------
__global__ void k_cvt_transpose(const float* __restrict__ src, bf16_t* __restrict__ dst,
                                int K, int N) {
    int idx = blockIdx.x * 256 + threadIdx.x;
    if (idx >= K * N) return;
    int k = idx / N, n = idx - k * N;
    dst[(size_t)n * K + k] = (bf16_t)src[idx];
}

__global__ void k_cvt_flat(const float* __restrict__ src, bf16_t* __restrict__ dst, int n) {
    int idx = blockIdx.x * 256 + threadIdx.x;
    if (idx >= n) return;
    dst[idx] = (bf16_t)src[idx];
}

__global__ void k_build_wrz(const float* __restrict__ Wih, const float* __restrict__ Whh,
                            const float* __restrict__ bih, const float* __restrict__ bhh,
                            bf16_t* __restrict__ wrz, float* __restrict__ brz) {
    int idx = blockIdx.x * 256 + threadIdx.x;
    if (idx >= 2048 * 1280) return;
    int n = idx / 1280, c = idx - n * 1280;
    float v = (c < 256) ? Wih[(size_t)n * 256 + c] : Whh[(size_t)n * 1024 + (c - 256)];
    wrz[idx] = (bf16_t)v;
    if (c == 0) brz[n] = bih[n] + bhh[n];
}

__global__ void k_cvt_x(const float* __restrict__ xt, bf16_t* __restrict__ xh, int B) {
    int idx = blockIdx.x * 256 + threadIdx.x;
    if (idx >= B * 256) return;
    int b = idx >> 8, c = idx & 255;
    xh[(size_t)b * 1280 + c] = (bf16_t)xt[idx];
}

__global__ void k_cvt_h0(const float* __restrict__ state, bf16_t* __restrict__ h0b, int B) {
    int idx = blockIdx.x * 256 + threadIdx.x;
    if (idx >= B * 1024) return;
    int b = idx >> 10, j = idx & 1023;
    h0b[idx] = (bf16_t)state[(size_t)b * 1040 + 16 + j];
}

// ---------------- GEMM: C(MxN) = A(MxK) * Bt(NxK)^T, bf16 in, f32 acc ----------------
// m201-style 8-phase template: 256x256 tile, BK=64, 512 threads (8 waves, 2M x 4N;
// wave = 128x64 output, acc[8][4]).  LDS = 2 dbuf x [2 kk-half x 256 x 32] per operand
// = 128 KiB.  Half-tile = one kk-half of A or B (16 KB = 2 global_load_lds issues).
// Per phase: {ds_read subtile, stage 1 half, barrier, lgkm0+sched_barrier, setprio,
// 16 MFMA quadrant, setprio, barrier}; counted vmcnt(6) only at phases 4 & 8.
// Slot-XOR swizzle slot^=((row>>1)&3), applied to BOTH staging source & ds_read
// (verified 0 bank conflicts, rounds 3-5).
enum { EPI_TANH = 0, EPI_RK4 = 1, EPI_SIG = 2, EPI_BIASBF = 3, EPI_FIN = 4 };

template <int EPI, int STAGE>
__global__ __launch_bounds__(512, 2) void gemm256(
    const bf16_t* __restrict__ A, int lda,
    const bf16_t* __restrict__ Bt,
    int N, int K,
    const float* __restrict__ bias,
    bf16_t* __restrict__ obf,
    const bf16_t* __restrict__ h0b,   // B x 1024 bf16 (RK4 stages 0-2)
    const float* __restrict__ state,  // f32, ld 1040 (RK4 stage 3 only)
    bf16_t* __restrict__ kacc,        // B x 1024 bf16 (k-sum)
    float* __restrict__ outp,         // f32 out, ld 1040
    bf16_t* __restrict__ xh_ht,       // = xh + 256 (ld 1280): stage-3 write / FIN ht read
    const bf16_t* __restrict__ rz,    // B x 2048 bf16 (FIN)
    const bf16_t* __restrict__ inb)   // B x 1024 bf16 (FIN)
{
    // [buf][kk][256 rows][32 elems]
    __shared__ __align__(16) bf16_t dsA[32768];
    __shared__ __align__(16) bf16_t dsB[32768];

    const int tid  = threadIdx.x;
    const int lane = tid & 63;
    const int wv   = tid >> 6;

    // XCD-aware bijective swizzle (all grids here have nwg % 8 == 0)
    const int gx  = gridDim.x;
    int bid = blockIdx.y * gx + blockIdx.x;
    const int nwg = gx * gridDim.y;
    if ((nwg & 7) == 0) {
        bid = (bid & 7) * (nwg >> 3) + (bid >> 3);
    }
    const int bm = (bid / gx) << 8;
    const int bn = (bid % gx) << 8;

    const int wm = (wv >> 2) << 7;   // 0 or 128
    const int wn = (wv & 3) << 6;    // 0,64,128,192

    f32x4 acc[8][4] = {};

    // ---- staging addresses (linear LDS dest, swizzled global source) ----
    const int srow  = tid >> 2;                        // 0..127
    const int sslot = tid & 3;
    const int ssw   = (sslot ^ ((srow >> 1) & 3)) << 3;  // swizzled col (elems)
    const bf16_t* gA_s = A  + (size_t)(bm + srow) * lda + ssw;
    const bf16_t* gB_s = Bt + (size_t)(bn + srow) * K + ssw;
    const size_t a128 = (size_t)128 * lda;
    const size_t b128 = (size_t)128 * K;
    const int dst0 = srow * 32 + sslot * 8;            // elems within a kk-plane
    // Halves: H0=A-kk0, H1=B-kk0, H2=A-kk1, H3=B-kk1.  2 loads/half/thread.
#define STG_A(t, kkv) do {                                                     \
        const int _pl = ((t) & 1) * 16384 + (kkv) * 8192;                      \
        const size_t _go = (size_t)(t) * 64 + (kkv) * 32;                      \
        async_cp16(gA_s + _go,        (void*)&dsA[_pl + dst0]);                \
        async_cp16(gA_s + a128 + _go, (void*)&dsA[_pl + dst0 + 4096]);         \
    } while (0)
#define STG_B(t, kkv) do {                                                     \
        const int _pl = ((t) & 1) * 16384 + (kkv) * 8192;                      \
        const size_t _go = (size_t)(t) * 64 + (kkv) * 32;                      \
        async_cp16(gB_s + _go,        (void*)&dsB[_pl + dst0]);                \
        async_cp16(gB_s + b128 + _go, (void*)&dsB[_pl + dst0 + 4096]);         \
    } while (0)

    // ---- fragment LDS offsets (within a kk-plane), swizzled read ----
    const int fr   = lane & 15;
    const int kg   = lane >> 4;
    const int frsw = (fr >> 1) & 3;
    const int aBase = (wm + fr) * 32 + ((kg ^ frsw) << 3);   // + i*512
    const int bBase = (wn + fr) * 32 + ((kg ^ frsw) << 3);   // + j*512

#define DS_A(dst, ih, kkv, bufv) do {                                          \
        const bf16_t* _p = &dsA[(bufv) * 16384 + (kkv) * 8192 + aBase + (ih) * 2048]; \
        dst[0] = *(const bf16x8*)(_p);                                         \
        dst[1] = *(const bf16x8*)(_p + 512);                                   \
        dst[2] = *(const bf16x8*)(_p + 1024);                                  \
        dst[3] = *(const bf16x8*)(_p + 1536);                                  \
    } while (0)
#define DS_B(dst, kkv, bufv) do {                                              \
        const bf16_t* _p = &dsB[(bufv) * 16384 + (kkv) * 8192 + bBase];        \
        dst[0] = *(const bf16x8*)(_p);                                         \
        dst[1] = *(const bf16x8*)(_p + 512);                                   \
        dst[2] = *(const bf16x8*)(_p + 1024);                                  \
        dst[3] = *(const bf16x8*)(_p + 1536);                                  \
    } while (0)

#define MFMA_Q(am, ib) do {                                                    \
        __builtin_amdgcn_s_setprio(1);                                         \
        _Pragma("unroll")                                                      \
        for (int x = 0; x < 4; ++x)                                            \
        _Pragma("unroll")                                                      \
        for (int j = 0; j < 4; ++j)                                            \
            acc[(ib) + x][j] = __builtin_amdgcn_mfma_f32_16x16x32_bf16(        \
                am[x], bF[j], acc[(ib) + x][j], 0, 0, 0);                      \
        __builtin_amdgcn_s_setprio(0);                                         \
    } while (0)

#define BAR()  __builtin_amdgcn_s_barrier()
#define LG0()  do { asm volatile("s_waitcnt lgkmcnt(0)" ::: "memory");         \
                    __builtin_amdgcn_sched_barrier(0); } while (0)

    const int NT = K >> 6;    // K-tiles (BK=64); all K here are multiples of 128
    const int NI = NT >> 1;   // iterations, 2 K-tiles each

    bf16x8 aL[4], aH[4], bF[4];

    // prologue: fully stage tiles 0 (buf0) and 1 (buf1): 16 loads/thread
    STG_A(0, 0); STG_B(0, 0); STG_A(0, 1); STG_B(0, 1);
    STG_A(1, 0); STG_B(1, 0); STG_A(1, 1); STG_B(1, 1);
    asm volatile("s_waitcnt vmcnt(8)" ::: "memory");   // tile 0 landed
    BAR();

    for (int s = 0; s < NI; ++s) {
        const int t1 = 2 * s + 1;
        const int ta = 2 * s + 2;
        const int tb = 2 * s + 3;
        const bool more = (s + 1 < NI);   // ta,tb < NT iff more

        // ---- P1: quad (i0-3, kk0) of buf0 ----
        DS_A(aL, 0, 0, 0); DS_B(bF, 0, 0);
        if (s > 0) STG_A(t1, 1);          // buf1 H2 (A-kk1), read at P7/P8
        BAR(); LG0(); MFMA_Q(aL, 0); BAR();
        // ---- P2: quad (i4-7, kk0) of buf0 ----
        DS_A(aH, 1, 0, 0);
        if (more) STG_B(ta, 0);           // buf0-next H1
        BAR(); LG0(); MFMA_Q(aH, 4); BAR();
        // ---- P3: quad (i0-3, kk1) of buf0 ----
        DS_A(aL, 0, 1, 0); DS_B(bF, 1, 0);
        if (more) STG_A(ta, 0);           // buf0-next H0
        BAR(); LG0(); MFMA_Q(aL, 0); BAR();
        // ---- P4: quad (i4-7, kk1) of buf0 + gate ----
        DS_A(aH, 1, 1, 0);
        if (more) STG_B(ta, 1);           // buf0-next H3
        BAR(); LG0(); MFMA_Q(aH, 4);
        if (more) asm volatile("s_waitcnt vmcnt(6)" ::: "memory");
        else      asm volatile("s_waitcnt vmcnt(0)" ::: "memory");
        BAR();
        // ---- P5: quad (i0-3, kk0) of buf1 ----
        DS_A(aL, 0, 0, 1); DS_B(bF, 0, 1);
        if (more) STG_A(ta, 1);           // buf0-next H2
        BAR(); LG0(); MFMA_Q(aL, 0); BAR();
        // ---- P6: quad (i4-7, kk0) of buf1 ----
        DS_A(aH, 1, 0, 1);
        if (more) STG_B(tb, 0);           // buf1-next H1
        BAR(); LG0(); MFMA_Q(aH, 4); BAR();
        // ---- P7: quad (i0-3, kk1) of buf1 ----
        DS_A(aL, 0, 1, 1); DS_B(bF, 1, 1);
        if (more) STG_A(tb, 0);           // buf1-next H0
        BAR(); LG0(); MFMA_Q(aL, 0); BAR();
        // ---- P8: quad (i4-7, kk1) of buf1 + gate ----
        DS_A(aH, 1, 1, 1);
        if (more) STG_B(tb, 1);           // buf1-next H3
        BAR(); LG0(); MFMA_Q(aH, 4);
        if (more) asm volatile("s_waitcnt vmcnt(6)" ::: "memory");
        else      asm volatile("s_waitcnt vmcnt(0)" ::: "memory");
        BAR();
    }
#undef STG_A
#undef STG_B
#undef DS_A
#undef DS_B
#undef MFMA_Q
#undef BAR
#undef LG0

    // C/D layout (verified m89/m91): col = lane&15, row = (lane>>4)*4 + reg
    const int orow0 = bm + wm + (kg << 2);
    const int ocol0 = bn + wn + fr;
#pragma unroll
    for (int i = 0; i < 8; ++i) {
#pragma unroll
        for (int j = 0; j < 4; ++j) {
#pragma unroll
            for (int r = 0; r < 4; ++r) {
                const int row = orow0 + i * 16 + r;
                const int col = ocol0 + j * 16;
                const float c = acc[i][j][r];
                if constexpr (EPI == EPI_TANH) {
                    obf[(size_t)row * N + col] = (bf16_t)fast_tanh(c + bias[col]);
                } else if constexpr (EPI == EPI_RK4) {
                    const float kk = c + bias[col];
                    const size_t hidx = ((size_t)row << 10) + col;
                    if constexpr (STAGE == 0) {
                        const float h0 = (float)h0b[hidx];
                        kacc[hidx] = (bf16_t)kk;
                        obf[hidx] = (bf16_t)(h0 + 0.05f * kk);
                    } else if constexpr (STAGE == 1) {
                        const float h0 = (float)h0b[hidx];
                        kacc[hidx] = (bf16_t)((float)kacc[hidx] + 2.f * kk);
                        obf[hidx] = (bf16_t)(h0 + 0.05f * kk);
                    } else if constexpr (STAGE == 2) {
                        const float h0 = (float)h0b[hidx];
                        kacc[hidx] = (bf16_t)((float)kacc[hidx] + 2.f * kk);
                        obf[hidx] = (bf16_t)(h0 + 0.1f * kk);
                    } else {
                        const float h0 = state[(size_t)row * 1040 + 16 + col];
                        const float ht = h0 + (0.1f / 6.f) * ((float)kacc[hidx] + kk);
                        outp[(size_t)row * 1040 + 16 + col] = ht;
                        xh_ht[(size_t)row * 1280 + col] = (bf16_t)ht;
                    }
                } else if constexpr (EPI == EPI_SIG) {
                    obf[(size_t)row * N + col] = (bf16_t)fast_sig(c + bias[col]);
                } else if constexpr (EPI == EPI_BIASBF) {
                    obf[(size_t)row * N + col] = (bf16_t)(c + bias[col]);
                } else {  // EPI_FIN
                    const float hn  = c + bias[col];
                    const float r_  = (float)rz[((size_t)row << 11) + col];
                    const float z_  = (float)rz[((size_t)row << 11) + 1024 + col];
                    const float inv = (float)inb[((size_t)row << 10) + col];
                    const float nn  = fast_tanh(inv + r_ * hn);
                    const float htv = (float)xh_ht[(size_t)row * 1280 + col];
                    outp[(size_t)row * 1040 + 16 + col] = (1.f - z_) * nn + z_ * htv;
                }
            }
        }
    }
}

// ---------------- readout: out[:, :16] ----------------
__global__ void k_ly(const float* __restrict__ outh, const float* __restrict__ state,
                     const float* __restrict__ Wly, const float* __restrict__ bly,
                     const int* __restrict__ y_type, float* __restrict__ outp, int B) {
    int t = blockIdx.x * 256 + threadIdx.x;
    if (t >= B * 16) return;
    int o = t & 15, b = t >> 4;
    const float4* hrow = (const float4*)(outh + (size_t)b * 1040 + 16);
    float s = bly[o];
#pragma unroll 4
    for (int k4 = 0; k4 < 256; ++k4) {
        float4 h = hrow[k4];
        int k = k4 << 2;
        s += h.x * Wly[(k + 0) * 16 + o] + h.y * Wly[(k + 1) * 16 + o]
           + h.z * Wly[(k + 2) * 16 + o] + h.w * Wly[(k + 3) * 16 + o];
    }
    outp[(size_t)b * 1040 + o] = (y_type[o] == 0) ? s : state[(size_t)b * 1040 + o];
}

// ---------------- launcher ----------------
extern "C" void kernel_launch(void* const* d_in, const int* in_sizes, int n_in,
                              void* d_out, int out_size, void* d_ws, size_t ws_size,
                              hipStream_t stream) {
    const float* state = (const float*)d_in[0];
    const float* xt    = (const float*)d_in[1];
    const float* W1    = (const float*)d_in[2];
    const float* b1    = (const float*)d_in[3];
    const float* W2    = (const float*)d_in[4];
    const float* b2    = (const float*)d_in[5];
    const float* Wih   = (const float*)d_in[6];
    const float* Whh   = (const float*)d_in[7];
    const float* bih   = (const float*)d_in[8];
    const float* bhh   = (const float*)d_in[9];
    const float* Wly   = (const float*)d_in[10];
    const float* bly   = (const float*)d_in[11];
    const int*   y_type = (const int*)d_in[12];
    float* out = (float*)d_out;

    const int B = in_sizes[0] / 1040;   // 32768

    char* ws = (char*)d_ws;
    bf16_t* w1t  = (bf16_t*)(ws);                    // 2048 x 1024
    bf16_t* w2t  = (bf16_t*)(ws + 4194304);          // 1024 x 2048
    bf16_t* wrz  = (bf16_t*)(ws + 8388608);          // 2048 x 1280
    bf16_t* win  = (bf16_t*)(ws + 13631488);         // 1024 x 256
    bf16_t* whn  = (bf16_t*)(ws + 14155776);         // 1024 x 1024
    float*  brz  = (float*) (ws + 16252928);         // 2048
    bf16_t* xh   = (bf16_t*)(ws + 16261120);         // B x 1280 ([x | ht_])
    bf16_t* hs   = (bf16_t*)(ws + 100147200);        // B x 1024 (RK4 stage input)
    bf16_t* h0b  = (bf16_t*)(ws + 167256064);        // B x 1024 (h0 bf16; later i_n)
    bf16_t* inbf = h0b;                              // i_n output reuses h0b space
    bf16_t* T    = (bf16_t*)(ws + 234364928);        // B x 2048 (tanh act; later r/z)
    bf16_t* kacc = (bf16_t*)(ws + 368582656);        // B x 1024 (k-sum, bf16)

    // weight prep + input casts
    k_cvt_transpose<<<(1024 * 2048) / 256, 256, 0, stream>>>(W1, w1t, 1024, 2048);
    k_cvt_transpose<<<(2048 * 1024) / 256, 256, 0, stream>>>(W2, w2t, 2048, 1024);
    k_build_wrz<<<(2048 * 1280) / 256, 256, 0, stream>>>(Wih, Whh, bih, bhh, wrz, brz);
    k_cvt_flat<<<(1024 * 256) / 256, 256, 0, stream>>>(Wih + 2048 * 256, win, 1024 * 256);
    k_cvt_flat<<<(1024 * 1024) / 256, 256, 0, stream>>>(Whh + 2048 * 1024, whn, 1024 * 1024);
    k_cvt_x<<<(B * 256) / 256, 256, 0, stream>>>(xt, xh, B);
    k_cvt_h0<<<(B * 1024) / 256, 256, 0, stream>>>(state, h0b, B);

    const dim3 blk(512);
    const int MB = B / 256;   // 128 m-tiles

    // ---- RK4: 4 stages of (tanh GEMM) -> (W2 GEMM + stage epilogue) ----
    gemm256<EPI_TANH, 0><<<dim3(8, MB), blk, 0, stream>>>(h0b, 1024, w1t, 2048, 1024, b1, T,
        nullptr, nullptr, nullptr, nullptr, nullptr, nullptr, nullptr);
    gemm256<EPI_RK4, 0><<<dim3(4, MB), blk, 0, stream>>>(T, 2048, w2t, 1024, 2048, b2, hs,
        h0b, state, kacc, out, xh + 256, nullptr, nullptr);

    gemm256<EPI_TANH, 0><<<dim3(8, MB), blk, 0, stream>>>(hs, 1024, w1t, 2048, 1024, b1, T,
        nullptr, nullptr, nullptr, nullptr, nullptr, nullptr, nullptr);
    gemm256<EPI_RK4, 1><<<dim3(4, MB), blk, 0, stream>>>(T, 2048, w2t, 1024, 2048, b2, hs,
        h0b, state, kacc, out, xh + 256, nullptr, nullptr);

    gemm256<EPI_TANH, 0><<<dim3(8, MB), blk, 0, stream>>>(hs, 1024, w1t, 2048, 1024, b1, T,
        nullptr, nullptr, nullptr, nullptr, nullptr, nullptr, nullptr);
    gemm256<EPI_RK4, 2><<<dim3(4, MB), blk, 0, stream>>>(T, 2048, w2t, 1024, 2048, b2, hs,
        h0b, state, kacc, out, xh + 256, nullptr, nullptr);

    gemm256<EPI_TANH, 0><<<dim3(8, MB), blk, 0, stream>>>(hs, 1024, w1t, 2048, 1024, b1, T,
        nullptr, nullptr, nullptr, nullptr, nullptr, nullptr, nullptr);
    gemm256<EPI_RK4, 3><<<dim3(4, MB), blk, 0, stream>>>(T, 2048, w2t, 1024, 2048, b2, hs,
        h0b, state, kacc, out, xh + 256, nullptr, nullptr);

    // ---- GRU ----
    gemm256<EPI_SIG, 0><<<dim3(8, MB), blk, 0, stream>>>(xh, 1280, wrz, 2048, 1280, brz, T,
        nullptr, nullptr, nullptr, nullptr, nullptr, nullptr, nullptr);
    gemm256<EPI_BIASBF, 0><<<dim3(4, MB), blk, 0, stream>>>(xh, 1280, win, 1024, 256,
        bih + 2048, inbf, nullptr, nullptr, nullptr, nullptr, nullptr, nullptr, nullptr);
    gemm256<EPI_FIN, 0><<<dim3(4, MB), blk, 0, stream>>>(xh + 256, 1280, whn, 1024, 1024,
        bhh + 2048, nullptr, nullptr, nullptr, nullptr, out, xh + 256, T, inbf);

    // ---- readout out[:, :16] ----
    k_ly<<<(B * 16) / 256, 256, 0, stream>>>(out, state, Wly, bly, y_type, out, B);
}

// Round 7
// 2311.162 us; speedup vs baseline: 1.1309x; 1.0270x over previous
//
#include <hip/hip_runtime.h>
#include <cstdint>
#include <cstddef>

typedef __bf16 bf16_t;
typedef __attribute__((ext_vector_type(8))) __bf16 bf16x8;
typedef __attribute__((ext_vector_type(4))) float f32x4;

__device__ __forceinline__ void async_cp16(const void* g, void* l) {
    __builtin_amdgcn_global_load_lds(
        (const __attribute__((address_space(1))) void*)g,
        (__attribute__((address_space(3))) void*)l,
        16, 0, 0);
}

// Inline-asm ds_read_b128 with compile-time offset immediate.  NO memory clobber:
// keeps LLVM's waitcnt pass from inserting alias-based vmcnt drains against the
// in-flight global_load_lds DMA (ordering is enforced by our own vmcnt ledger +
// lgkmcnt(0)+sched_barrier(0) per rule 18).
template <int OFF>
__device__ __forceinline__ bf16x8 dsr128(unsigned addr) {
    bf16x8 out;
    asm volatile("ds_read_b128 %0, %1 offset:%2"
                 : "=v"(out) : "v"(addr), "i"(OFF));
    return out;
}

__device__ __forceinline__ float fast_tanh(float x) {
    float ax = fabsf(x);
    float e = __expf(-2.f * ax);
    float t = (1.f - e) / (1.f + e);
    return x < 0.f ? -t : t;
}
__device__ __forceinline__ float fast_sig(float x) {
    return 1.f / (1.f + __expf(-x));
}

// ---------------- conversion kernels ----------------
__global__ void k_cvt_transpose(const float* __restrict__ src, bf16_t* __restrict__ dst,
                                int K, int N) {
    int idx = blockIdx.x * 256 + threadIdx.x;
    if (idx >= K * N) return;
    int k = idx / N, n = idx - k * N;
    dst[(size_t)n * K + k] = (bf16_t)src[idx];
}

__global__ void k_cvt_flat(const float* __restrict__ src, bf16_t* __restrict__ dst, int n) {
    int idx = blockIdx.x * 256 + threadIdx.x;
    if (idx >= n) return;
    dst[idx] = (bf16_t)src[idx];
}

__global__ void k_build_wrz(const float* __restrict__ Wih, const float* __restrict__ Whh,
                            const float* __restrict__ bih, const float* __restrict__ bhh,
                            bf16_t* __restrict__ wrz, float* __restrict__ brz) {
    int idx = blockIdx.x * 256 + threadIdx.x;
    if (idx >= 2048 * 1280) return;
    int n = idx / 1280, c = idx - n * 1280;
    float v = (c < 256) ? Wih[(size_t)n * 256 + c] : Whh[(size_t)n * 1024 + (c - 256)];
    wrz[idx] = (bf16_t)v;
    if (c == 0) brz[n] = bih[n] + bhh[n];
}

__global__ void k_cvt_x(const float* __restrict__ xt, bf16_t* __restrict__ xh, int B) {
    int idx = blockIdx.x * 256 + threadIdx.x;
    if (idx >= B * 256) return;
    int b = idx >> 8, c = idx & 255;
    xh[(size_t)b * 1280 + c] = (bf16_t)xt[idx];
}

__global__ void k_cvt_h0(const float* __restrict__ state, bf16_t* __restrict__ h0b, int B) {
    int idx = blockIdx.x * 256 + threadIdx.x;
    if (idx >= B * 1024) return;
    int b = idx >> 10, j = idx & 1023;
    h0b[idx] = (bf16_t)state[(size_t)b * 1040 + 16 + j];
}

// ---------------- GEMM: C(MxN) = A(MxK) * Bt(NxK)^T, bf16 in, f32 acc ----------------
// 8-phase template (round 6 structure, verified ledger) with inline-asm ds_read_b128
// fragment loads (no compiler alias-drains).  256x256 tile, BK=64, 512 threads
// (8 waves, 2M x 4N; wave = 128x64, acc[8][4]).  LDS 128 KiB = 2 dbuf x 2 kk-half.
// Counted vmcnt(6) only at phases 4 & 8.  Slot-XOR swizzle (0 conflicts, verified).
enum { EPI_TANH = 0, EPI_RK4 = 1, EPI_SIG = 2, EPI_BIASBF = 3, EPI_FIN = 4 };

template <int EPI, int STAGE>
__global__ __launch_bounds__(512, 2) void gemm256(
    const bf16_t* __restrict__ A, int lda,
    const bf16_t* __restrict__ Bt,
    int N, int K,
    const float* __restrict__ bias,
    bf16_t* __restrict__ obf,
    const bf16_t* __restrict__ h0b,   // B x 1024 bf16 (RK4 stages 0-2)
    const float* __restrict__ state,  // f32, ld 1040 (RK4 stage 3 only)
    bf16_t* __restrict__ kacc,        // B x 1024 bf16 (k-sum)
    float* __restrict__ outp,         // f32 out, ld 1040
    bf16_t* __restrict__ xh_ht,       // = xh + 256 (ld 1280): stage-3 write / FIN ht read
    const bf16_t* __restrict__ rz,    // B x 2048 bf16 (FIN)
    const bf16_t* __restrict__ inb)   // B x 1024 bf16 (FIN)
{
    // [buf][kk][256 rows][32 elems]
    __shared__ __align__(16) bf16_t dsA[32768];
    __shared__ __align__(16) bf16_t dsB[32768];

    const int tid  = threadIdx.x;
    const int lane = tid & 63;
    const int wv   = tid >> 6;

    // XCD-aware bijective swizzle (all grids here have nwg % 8 == 0)
    const int gx  = gridDim.x;
    int bid = blockIdx.y * gx + blockIdx.x;
    const int nwg = gx * gridDim.y;
    if ((nwg & 7) == 0) {
        bid = (bid & 7) * (nwg >> 3) + (bid >> 3);
    }
    const int bm = (bid / gx) << 8;
    const int bn = (bid % gx) << 8;

    const int wm = (wv >> 2) << 7;   // 0 or 128
    const int wn = (wv & 3) << 6;    // 0,64,128,192

    f32x4 acc[8][4] = {};

    // ---- staging addresses (linear LDS dest, swizzled global source) ----
    const int srow  = tid >> 2;                        // 0..127
    const int sslot = tid & 3;
    const int ssw   = (sslot ^ ((srow >> 1) & 3)) << 3;  // swizzled col (elems)
    const bf16_t* gA_s = A  + (size_t)(bm + srow) * lda + ssw;
    const bf16_t* gB_s = Bt + (size_t)(bn + srow) * K + ssw;
    const size_t a128 = (size_t)128 * lda;
    const size_t b128 = (size_t)128 * K;
    const int dst0 = srow * 32 + sslot * 8;            // elems within a kk-plane
    // Halves: H0=A-kk0, H1=B-kk0, H2=A-kk1, H3=B-kk1.  2 loads/half/thread.
#define STG_A(t, kkv) do {                                                     \
        const int _pl = ((t) & 1) * 16384 + (kkv) * 8192;                      \
        const size_t _go = (size_t)(t) * 64 + (kkv) * 32;                      \
        async_cp16(gA_s + _go,        (void*)&dsA[_pl + dst0]);                \
        async_cp16(gA_s + a128 + _go, (void*)&dsA[_pl + dst0 + 4096]);         \
    } while (0)
#define STG_B(t, kkv) do {                                                     \
        const int _pl = ((t) & 1) * 16384 + (kkv) * 8192;                      \
        const size_t _go = (size_t)(t) * 64 + (kkv) * 32;                      \
        async_cp16(gB_s + _go,        (void*)&dsB[_pl + dst0]);                \
        async_cp16(gB_s + b128 + _go, (void*)&dsB[_pl + dst0 + 4096]);         \
    } while (0)

    // ---- fragment LDS base addresses (bytes), swizzled read ----
    const int fr   = lane & 15;
    const int kg   = lane >> 4;
    const int frsw = (fr >> 1) & 3;
    const int aBase = (wm + fr) * 32 + ((kg ^ frsw) << 3);   // elem idx, + i*512
    const int bBase = (wn + fr) * 32 + ((kg ^ frsw) << 3);
    const unsigned aAddr = (unsigned)(size_t)&dsA[aBase];
    const unsigned bAddr = (unsigned)(size_t)&dsB[bBase];

    // byte offsets: buf 32768, kk-plane 16384, ih (4 rows of 16) 4096, quad 1024
#define DS_A(dst, ih, kkv, bufv) do {                                          \
        dst[0] = dsr128<(bufv)*32768 + (kkv)*16384 + (ih)*4096 +    0>(aAddr); \
        dst[1] = dsr128<(bufv)*32768 + (kkv)*16384 + (ih)*4096 + 1024>(aAddr); \
        dst[2] = dsr128<(bufv)*32768 + (kkv)*16384 + (ih)*4096 + 2048>(aAddr); \
        dst[3] = dsr128<(bufv)*32768 + (kkv)*16384 + (ih)*4096 + 3072>(aAddr); \
    } while (0)
#define DS_B(dst, kkv, bufv) do {                                              \
        dst[0] = dsr128<(bufv)*32768 + (kkv)*16384 +    0>(bAddr);             \
        dst[1] = dsr128<(bufv)*32768 + (kkv)*16384 + 1024>(bAddr);             \
        dst[2] = dsr128<(bufv)*32768 + (kkv)*16384 + 2048>(bAddr);             \
        dst[3] = dsr128<(bufv)*32768 + (kkv)*16384 + 3072>(bAddr);             \
    } while (0)

#define MFMA_Q(am, ib) do {                                                    \
        __builtin_amdgcn_s_setprio(1);                                         \
        _Pragma("unroll")                                                      \
        for (int x = 0; x < 4; ++x)                                            \
        _Pragma("unroll")                                                      \
        for (int j = 0; j < 4; ++j)                                            \
            acc[(ib) + x][j] = __builtin_amdgcn_mfma_f32_16x16x32_bf16(        \
                am[x], bF[j], acc[(ib) + x][j], 0, 0, 0);                      \
        __builtin_amdgcn_s_setprio(0);                                         \
    } while (0)

#define BAR()  __builtin_amdgcn_s_barrier()
#define LG0()  do { asm volatile("s_waitcnt lgkmcnt(0)" ::: "memory");         \
                    __builtin_amdgcn_sched_barrier(0); } while (0)

    const int NT = K >> 6;    // K-tiles (BK=64); all K here are multiples of 128
    const int NI = NT >> 1;   // iterations, 2 K-tiles each

    bf16x8 aL[4], aH[4], bF[4];

    // prologue: fully stage tiles 0 (buf0) and 1 (buf1): 16 loads/thread
    STG_A(0, 0); STG_B(0, 0); STG_A(0, 1); STG_B(0, 1);
    STG_A(1, 0); STG_B(1, 0); STG_A(1, 1); STG_B(1, 1);
    asm volatile("s_waitcnt vmcnt(8)" ::: "memory");   // tile 0 landed
    BAR();

    for (int s = 0; s < NI; ++s) {
        const int t1 = 2 * s + 1;
        const int ta = 2 * s + 2;
        const int tb = 2 * s + 3;
        const bool more = (s + 1 < NI);   // ta,tb < NT iff more

        // ---- P1: quad (i0-3, kk0) of buf0 ----
        DS_A(aL, 0, 0, 0); DS_B(bF, 0, 0);
        if (s > 0) STG_A(t1, 1);          // buf1 H2 (A-kk1), read at P7/P8
        BAR(); LG0(); MFMA_Q(aL, 0); BAR();
        // ---- P2: quad (i4-7, kk0) of buf0 ----
        DS_A(aH, 1, 0, 0);
        if (more) STG_B(ta, 0);           // buf0-next H1
        BAR(); LG0(); MFMA_Q(aH, 4); BAR();
        // ---- P3: quad (i0-3, kk1) of buf0 ----
        DS_A(aL, 0, 1, 0); DS_B(bF, 1, 0);
        if (more) STG_A(ta, 0);           // buf0-next H0
        BAR(); LG0(); MFMA_Q(aL, 0); BAR();
        // ---- P4: quad (i4-7, kk1) of buf0 + gate ----
        DS_A(aH, 1, 1, 0);
        if (more) STG_B(ta, 1);           // buf0-next H3
        BAR(); LG0(); MFMA_Q(aH, 4);
        if (more) asm volatile("s_waitcnt vmcnt(6)" ::: "memory");
        else      asm volatile("s_waitcnt vmcnt(0)" ::: "memory");
        BAR();
        // ---- P5: quad (i0-3, kk0) of buf1 ----
        DS_A(aL, 0, 0, 1); DS_B(bF, 0, 1);
        if (more) STG_A(ta, 1);           // buf0-next H2
        BAR(); LG0(); MFMA_Q(aL, 0); BAR();
        // ---- P6: quad (i4-7, kk0) of buf1 ----
        DS_A(aH, 1, 0, 1);
        if (more) STG_B(tb, 0);           // buf1-next H1
        BAR(); LG0(); MFMA_Q(aH, 4); BAR();
        // ---- P7: quad (i0-3, kk1) of buf1 ----
        DS_A(aL, 0, 1, 1); DS_B(bF, 1, 1);
        if (more) STG_A(tb, 0);           // buf1-next H0
        BAR(); LG0(); MFMA_Q(aL, 0); BAR();
        // ---- P8: quad (i4-7, kk1) of buf1 + gate ----
        DS_A(aH, 1, 1, 1);
        if (more) STG_B(tb, 1);           // buf1-next H3
        BAR(); LG0(); MFMA_Q(aH, 4);
        if (more) asm volatile("s_waitcnt vmcnt(6)" ::: "memory");
        else      asm volatile("s_waitcnt vmcnt(0)" ::: "memory");
        BAR();
    }
#undef STG_A
#undef STG_B
#undef DS_A
#undef DS_B
#undef MFMA_Q
#undef BAR
#undef LG0

    // C/D layout (verified m89/m91): col = lane&15, row = (lane>>4)*4 + reg
    const int orow0 = bm + wm + (kg << 2);
    const int ocol0 = bn + wn + fr;
#pragma unroll
    for (int i = 0; i < 8; ++i) {
#pragma unroll
        for (int j = 0; j < 4; ++j) {
#pragma unroll
            for (int r = 0; r < 4; ++r) {
                const int row = orow0 + i * 16 + r;
                const int col = ocol0 + j * 16;
                const float c = acc[i][j][r];
                if constexpr (EPI == EPI_TANH) {
                    obf[(size_t)row * N + col] = (bf16_t)fast_tanh(c + bias[col]);
                } else if constexpr (EPI == EPI_RK4) {
                    const float kk = c + bias[col];
                    const size_t hidx = ((size_t)row << 10) + col;
                    if constexpr (STAGE == 0) {
                        const float h0 = (float)h0b[hidx];
                        kacc[hidx] = (bf16_t)kk;
                        obf[hidx] = (bf16_t)(h0 + 0.05f * kk);
                    } else if constexpr (STAGE == 1) {
                        const float h0 = (float)h0b[hidx];
                        kacc[hidx] = (bf16_t)((float)kacc[hidx] + 2.f * kk);
                        obf[hidx] = (bf16_t)(h0 + 0.05f * kk);
                    } else if constexpr (STAGE == 2) {
                        const float h0 = (float)h0b[hidx];
                        kacc[hidx] = (bf16_t)((float)kacc[hidx] + 2.f * kk);
                        obf[hidx] = (bf16_t)(h0 + 0.1f * kk);
                    } else {
                        const float h0 = state[(size_t)row * 1040 + 16 + col];
                        const float ht = h0 + (0.1f / 6.f) * ((float)kacc[hidx] + kk);
                        outp[(size_t)row * 1040 + 16 + col] = ht;
                        xh_ht[(size_t)row * 1280 + col] = (bf16_t)ht;
                    }
                } else if constexpr (EPI == EPI_SIG) {
                    obf[(size_t)row * N + col] = (bf16_t)fast_sig(c + bias[col]);
                } else if constexpr (EPI == EPI_BIASBF) {
                    obf[(size_t)row * N + col] = (bf16_t)(c + bias[col]);
                } else {  // EPI_FIN
                    const float hn  = c + bias[col];
                    const float r_  = (float)rz[((size_t)row << 11) + col];
                    const float z_  = (float)rz[((size_t)row << 11) + 1024 + col];
                    const float inv = (float)inb[((size_t)row << 10) + col];
                    const float nn  = fast_tanh(inv + r_ * hn);
                    const float htv = (float)xh_ht[(size_t)row * 1280 + col];
                    outp[(size_t)row * 1040 + 16 + col] = (1.f - z_) * nn + z_ * htv;
                }
            }
        }
    }
}

// ---------------- readout: out[:, :16] ----------------
__global__ void k_ly(const float* __restrict__ outh, const float* __restrict__ state,
                     const float* __restrict__ Wly, const float* __restrict__ bly,
                     const int* __restrict__ y_type, float* __restrict__ outp, int B) {
    int t = blockIdx.x * 256 + threadIdx.x;
    if (t >= B * 16) return;
    int o = t & 15, b = t >> 4;
    const float4* hrow = (const float4*)(outh + (size_t)b * 1040 + 16);
    float s = bly[o];
#pragma unroll 4
    for (int k4 = 0; k4 < 256; ++k4) {
        float4 h = hrow[k4];
        int k = k4 << 2;
        s += h.x * Wly[(k + 0) * 16 + o] + h.y * Wly[(k + 1) * 16 + o]
           + h.z * Wly[(k + 2) * 16 + o] + h.w * Wly[(k + 3) * 16 + o];
    }
    outp[(size_t)b * 1040 + o] = (y_type[o] == 0) ? s : state[(size_t)b * 1040 + o];
}

// ---------------- launcher ----------------
extern "C" void kernel_launch(void* const* d_in, const int* in_sizes, int n_in,
                              void* d_out, int out_size, void* d_ws, size_t ws_size,
                              hipStream_t stream) {
    const float* state = (const float*)d_in[0];
    const float* xt    = (const float*)d_in[1];
    const float* W1    = (const float*)d_in[2];
    const float* b1    = (const float*)d_in[3];
    const float* W2    = (const float*)d_in[4];
    const float* b2    = (const float*)d_in[5];
    const float* Wih   = (const float*)d_in[6];
    const float* Whh   = (const float*)d_in[7];
    const float* bih   = (const float*)d_in[8];
    const float* bhh   = (const float*)d_in[9];
    const float* Wly   = (const float*)d_in[10];
    const float* bly   = (const float*)d_in[11];
    const int*   y_type = (const int*)d_in[12];
    float* out = (float*)d_out;

    const int B = in_sizes[0] / 1040;   // 32768

    char* ws = (char*)d_ws;
    bf16_t* w1t  = (bf16_t*)(ws);                    // 2048 x 1024
    bf16_t* w2t  = (bf16_t*)(ws + 4194304);          // 1024 x 2048
    bf16_t* wrz  = (bf16_t*)(ws + 8388608);          // 2048 x 1280
    bf16_t* win  = (bf16_t*)(ws + 13631488);         // 1024 x 256
    bf16_t* whn  = (bf16_t*)(ws + 14155776);         // 1024 x 1024
    float*  brz  = (float*) (ws + 16252928);         // 2048
    bf16_t* xh   = (bf16_t*)(ws + 16261120);         // B x 1280 ([x | ht_])
    bf16_t* hs   = (bf16_t*)(ws + 100147200);        // B x 1024 (RK4 stage input)
    bf16_t* h0b  = (bf16_t*)(ws + 167256064);        // B x 1024 (h0 bf16; later i_n)
    bf16_t* inbf = h0b;                              // i_n output reuses h0b space
    bf16_t* T    = (bf16_t*)(ws + 234364928);        // B x 2048 (tanh act; later r/z)
    bf16_t* kacc = (bf16_t*)(ws + 368582656);        // B x 1024 (k-sum, bf16)

    // weight prep + input casts
    k_cvt_transpose<<<(1024 * 2048) / 256, 256, 0, stream>>>(W1, w1t, 1024, 2048);
    k_cvt_transpose<<<(2048 * 1024) / 256, 256, 0, stream>>>(W2, w2t, 2048, 1024);
    k_build_wrz<<<(2048 * 1280) / 256, 256, 0, stream>>>(Wih, Whh, bih, bhh, wrz, brz);
    k_cvt_flat<<<(1024 * 256) / 256, 256, 0, stream>>>(Wih + 2048 * 256, win, 1024 * 256);
    k_cvt_flat<<<(1024 * 1024) / 256, 256, 0, stream>>>(Whh + 2048 * 1024, whn, 1024 * 1024);
    k_cvt_x<<<(B * 256) / 256, 256, 0, stream>>>(xt, xh, B);
    k_cvt_h0<<<(B * 1024) / 256, 256, 0, stream>>>(state, h0b, B);

    const dim3 blk(512);
    const int MB = B / 256;   // 128 m-tiles

    // ---- RK4: 4 stages of (tanh GEMM) -> (W2 GEMM + stage epilogue) ----
    gemm256<EPI_TANH, 0><<<dim3(8, MB), blk, 0, stream>>>(h0b, 1024, w1t, 2048, 1024, b1, T,
        nullptr, nullptr, nullptr, nullptr, nullptr, nullptr, nullptr);
    gemm256<EPI_RK4, 0><<<dim3(4, MB), blk, 0, stream>>>(T, 2048, w2t, 1024, 2048, b2, hs,
        h0b, state, kacc, out, xh + 256, nullptr, nullptr);

    gemm256<EPI_TANH, 0><<<dim3(8, MB), blk, 0, stream>>>(hs, 1024, w1t, 2048, 1024, b1, T,
        nullptr, nullptr, nullptr, nullptr, nullptr, nullptr, nullptr);
    gemm256<EPI_RK4, 1><<<dim3(4, MB), blk, 0, stream>>>(T, 2048, w2t, 1024, 2048, b2, hs,
        h0b, state, kacc, out, xh + 256, nullptr, nullptr);

    gemm256<EPI_TANH, 0><<<dim3(8, MB), blk, 0, stream>>>(hs, 1024, w1t, 2048, 1024, b1, T,
        nullptr, nullptr, nullptr, nullptr, nullptr, nullptr, nullptr);
    gemm256<EPI_RK4, 2><<<dim3(4, MB), blk, 0, stream>>>(T, 2048, w2t, 1024, 2048, b2, hs,
        h0b, state, kacc, out, xh + 256, nullptr, nullptr);

    gemm256<EPI_TANH, 0><<<dim3(8, MB), blk, 0, stream>>>(hs, 1024, w1t, 2048, 1024, b1, T,
        nullptr, nullptr, nullptr, nullptr, nullptr, nullptr, nullptr);
    gemm256<EPI_RK4, 3><<<dim3(4, MB), blk, 0, stream>>>(T, 2048, w2t, 1024, 2048, b2, hs,
        h0b, state, kacc, out, xh + 256, nullptr, nullptr);

    // ---- GRU ----
    gemm256<EPI_SIG, 0><<<dim3(8, MB), blk, 0, stream>>>(xh, 1280, wrz, 2048, 1280, brz, T,
        nullptr, nullptr, nullptr, nullptr, nullptr, nullptr, nullptr);
    gemm256<EPI_BIASBF, 0><<<dim3(4, MB), blk, 0, stream>>>(xh, 1280, win, 1024, 256,
        bih + 2048, inbf, nullptr, nullptr, nullptr, nullptr, nullptr, nullptr, nullptr);
    gemm256<EPI_FIN, 0><<<dim3(4, MB), blk, 0, stream>>>(xh + 256, 1280, whn, 1024, 1024,
        bhh + 2048, nullptr, nullptr, nullptr, nullptr, out, xh + 256, T, inbf);

    // ---- readout out[:, :16] ----
    k_ly<<<(B * 16) / 256, 256, 0, stream>>>(out, state, Wly, bly, y_type, out, B);
}